// Round 1
// baseline (124.067 us; speedup 1.0000x reference)
//
#include <hip/hip_runtime.h>

#define ROWS_ 131072      // S*N*B = 16*256*32
#define NNZ_  524288
#define E_    256
#define E4_   64          // E/4 float4s per row

// ---------------------------------------------------------------------------
// Kernel A: dense embedding gather. One thread per output float4.
// 64 consecutive threads share a row -> node_idx load is wave-uniform,
// table row (1 KiB) is L1/L2 resident, output write fully coalesced.
// ---------------------------------------------------------------------------
__global__ void node_embed_kernel(const int* __restrict__ node_idx,
                                  const float4* __restrict__ w,
                                  float4* __restrict__ out) {
    int tid = blockIdx.x * blockDim.x + threadIdx.x;   // one float4 each
    int row = tid >> 6;          // which of ROWS_ rows
    int l   = tid & 63;          // which float4 within E=256
    int node = node_idx[row];
    out[tid] = w[node * E4_ + l];
}

// ---------------------------------------------------------------------------
// Kernel B: build CSR-style row_start[] from sorted COO rows via binary
// search. One thread per output row (plus one for the sentinel r==ROWS_,
// which finds lo == NNZ_ since all stored rows < ROWS_).
// ---------------------------------------------------------------------------
__global__ void row_ptr_kernel(const int* __restrict__ rows,
                               int* __restrict__ row_start) {
    int r = blockIdx.x * blockDim.x + threadIdx.x;
    if (r > ROWS_) return;
    int lo = 0, hi = NNZ_;
    while (lo < hi) {
        int mid = (lo + hi) >> 1;
        if (rows[mid] < r) lo = mid + 1;
        else hi = mid;
    }
    row_start[r] = lo;
}

// ---------------------------------------------------------------------------
// Kernel C: SpMM segment-sum. One wave (64 lanes) per output row; each lane
// owns one float4 (4 columns) of E=256. Per nnz: wave-uniform col/val load,
// coalesced 1 KiB gather from val_tok_embed, FMA into registers. One
// non-atomic coalesced write per row. Rows with no nnz write zeros.
// ---------------------------------------------------------------------------
__global__ void spmm_kernel(const int* __restrict__ row_start,
                            const int* __restrict__ cols,
                            const float* __restrict__ vals,
                            const float4* __restrict__ tok,
                            float4* __restrict__ out) {
    int gtid = blockIdx.x * blockDim.x + threadIdx.x;
    int row  = gtid >> 6;
    int lane = threadIdx.x & 63;
    if (row >= ROWS_) return;

    int start = row_start[row];
    int end   = row_start[row + 1];

    float4 acc = make_float4(0.f, 0.f, 0.f, 0.f);
    for (int i = start; i < end; ++i) {
        int   c = cols[i];     // wave-uniform
        float v = vals[i];     // wave-uniform
        float4 t = tok[c * E4_ + lane];
        acc.x += v * t.x;
        acc.y += v * t.y;
        acc.z += v * t.z;
        acc.w += v * t.w;
    }
    out[(size_t)row * E4_ + lane] = acc;
}

extern "C" void kernel_launch(void* const* d_in, const int* in_sizes, int n_in,
                              void* d_out, int out_size, void* d_ws, size_t ws_size,
                              hipStream_t stream) {
    const int*   node_idx  = (const int*)d_in[0];
    const int*   spmm_rows = (const int*)d_in[1];
    const int*   spmm_cols = (const int*)d_in[2];
    const float* spmm_vals = (const float*)d_in[3];
    const float* node_w    = (const float*)d_in[4];
    const float* tok       = (const float*)d_in[5];

    float* out1 = (float*)d_out;                          // node_embed
    float* out2 = out1 + (size_t)ROWS_ * E_;              // node_val_embed
    int*   row_start = (int*)d_ws;                        // (ROWS_+1) ints

    // A: 131072 rows * 64 float4 = 8.39M threads
    node_embed_kernel<<<(ROWS_ * E4_) / 256, 256, 0, stream>>>(
        node_idx, (const float4*)node_w, (float4*)out1);

    // B: ROWS_+1 binary searches
    row_ptr_kernel<<<(ROWS_ + 1 + 255) / 256, 256, 0, stream>>>(
        spmm_rows, row_start);

    // C: one wave per row, 4 waves per block
    spmm_kernel<<<ROWS_ / 4, 256, 0, stream>>>(
        row_start, spmm_cols, spmm_vals, (const float4*)tok, (float4*)out2);
}